// Round 1
// baseline (443.671 us; speedup 1.0000x reference)
//
#include <hip/hip_runtime.h>
#include <hip/hip_bf16.h>

// GAT self-attention: Wh = h@W; out = softmax(leaky_relu(Wh@Wh^T)) @ Wh
// N=8192, IN_F=256, OUT_F=128. adj input unused by the math.
//
// Plan: fp32 Wh -> f16 (and f16 Wh^T) in ws; flash-attention over S=8192,
// D=128 with mfma_f32_16x16x32_f16; 4-way key-split for occupancy (512
// blocks on 256 CUs); fp32 log-sum-exp combine.

#define SEQ   8192
#define DIM   128
#define IN_F  256
#define BM    64
#define BN    64
#define NSPLIT 4
#define JITER ((SEQ / NSPLIT) / BN)   // 32

typedef __attribute__((ext_vector_type(8))) _Float16 f16x8;
typedef __attribute__((ext_vector_type(4))) _Float16 f16x4;
typedef __attribute__((ext_vector_type(4))) float   floatx4;

// ---------------------------------------------------------------------------
// Kernel 1: Wh = h @ W (fp32 accum), emit Wh (f16, row-major) and Wh^T (f16)
// block = 256 threads = 8 rows x 32 col-groups(float4). 1024 blocks.
// ---------------------------------------------------------------------------
__global__ __launch_bounds__(256) void wh_kernel(
    const float* __restrict__ h, const float* __restrict__ W,
    _Float16* __restrict__ Wh16, _Float16* __restrict__ WhT16) {
  int tid = threadIdx.x;
  int cg  = tid & 31;         // column group: 4 fp32 cols
  int rl  = tid >> 5;         // 0..7
  int row = blockIdx.x * 8 + rl;
  const float4* W4 = (const float4*)W;          // [256][32] of float4
  const float4* h4 = (const float4*)(h + (size_t)row * IN_F);
  float4 acc = make_float4(0.f, 0.f, 0.f, 0.f);
#pragma unroll 8
  for (int k4 = 0; k4 < IN_F / 4; k4++) {
    float4 hv = h4[k4];
    float4 w0 = W4[(k4 * 4 + 0) * 32 + cg];
    float4 w1 = W4[(k4 * 4 + 1) * 32 + cg];
    float4 w2 = W4[(k4 * 4 + 2) * 32 + cg];
    float4 w3 = W4[(k4 * 4 + 3) * 32 + cg];
    acc.x += hv.x * w0.x + hv.y * w1.x + hv.z * w2.x + hv.w * w3.x;
    acc.y += hv.x * w0.y + hv.y * w1.y + hv.z * w2.y + hv.w * w3.y;
    acc.z += hv.x * w0.z + hv.y * w1.z + hv.z * w2.z + hv.w * w3.z;
    acc.w += hv.x * w0.w + hv.y * w1.w + hv.z * w2.w + hv.w * w3.w;
  }
  f16x4 r;
  r[0] = (_Float16)acc.x; r[1] = (_Float16)acc.y;
  r[2] = (_Float16)acc.z; r[3] = (_Float16)acc.w;
  *(f16x4*)&Wh16[(size_t)row * DIM + cg * 4] = r;
#pragma unroll
  for (int j = 0; j < 4; j++)
    WhT16[(size_t)(cg * 4 + j) * SEQ + row] = r[j];
}

// ---------------------------------------------------------------------------
// Kernel 2: flash attention. grid = (128 qtiles, NSPLIT), block = 256 (4 waves)
// wave w owns Q rows [qtile*64 + w*16, +16). Iterate 64-key tiles.
// LDS: Ksh [64][136] halves (row-major keys), Vtsh [128][72] (col-major = V^T),
//      Psh [4 waves][16][72] for the C->A layout round trip.
// ---------------------------------------------------------------------------
__global__ __launch_bounds__(256) void flash_kernel(
    const _Float16* __restrict__ Wh16, const _Float16* __restrict__ WhT16,
    float* __restrict__ Opart, float* __restrict__ mpart,
    float* __restrict__ lpart) {
  __shared__ _Float16 lds[22528];           // 45056 B
  _Float16* Ksh  = lds;                     // 64*136  = 8704 halves
  _Float16* Vtsh = lds + 8704;              // 128*72  = 9216
  _Float16* Psh  = lds + 8704 + 9216;       // 4*16*72 = 4608

  const int tid  = threadIdx.x;
  const int lane = tid & 63;
  const int wave = tid >> 6;
  const int n16  = lane & 15;
  const int quad = lane >> 4;

  const int qbase  = blockIdx.x * BM + wave * 16;
  const int jbase0 = blockIdx.y * (SEQ / NSPLIT);

  // Q A-fragments, resident for the whole loop: A[m=lane&15][k=quad*8+j+32c]
  f16x8 qf[4];
#pragma unroll
  for (int c = 0; c < 4; c++)
    qf[c] = *(const f16x8*)&Wh16[(size_t)(qbase + n16) * DIM + c * 32 + quad * 8];

  floatx4 o[8];
#pragma unroll
  for (int ct = 0; ct < 8; ct++) o[ct] = (floatx4){0.f, 0.f, 0.f, 0.f};
  float m_run[4], l_run[4];
#pragma unroll
  for (int e = 0; e < 4; e++) { m_run[e] = -1e30f; l_run[e] = 0.f; }

  for (int it = 0; it < JITER; it++) {
    const int jbase = jbase0 + it * BN;
    __syncthreads();   // previous iter's K/Vt reads done before overwrite
    // ---- stage K-tile (row-major) and V^T-tile; 4 x f16x8 each per thread
#pragma unroll
    for (int rep = 0; rep < 4; rep++) {
      int v = rep * 256 + tid;              // 0..1023 vector slots
      int krow = v >> 4, kcol = (v & 15) * 8;
      *(f16x8*)&Ksh[krow * 136 + kcol] =
          *(const f16x8*)&Wh16[(size_t)(jbase + krow) * DIM + kcol];
      int vd = v >> 3, vcol = (v & 7) * 8;
      *(f16x8*)&Vtsh[vd * 72 + vcol] =
          *(const f16x8*)&WhT16[(size_t)vd * SEQ + jbase + vcol];
    }
    __syncthreads();

    // ---- S = Q K^T : 4 key-subtiles x 4 k-chunks
    floatx4 s[4];
#pragma unroll
    for (int t = 0; t < 4; t++) {
      s[t] = (floatx4){0.f, 0.f, 0.f, 0.f};
#pragma unroll
      for (int c = 0; c < 4; c++) {
        f16x8 kf = *(const f16x8*)&Ksh[(t * 16 + n16) * 136 + c * 32 + quad * 8];
        s[t] = __builtin_amdgcn_mfma_f32_16x16x32_f16(qf[c], kf, s[t], 0, 0, 0);
      }
    }
    // ---- leaky_relu(0.2)
#pragma unroll
    for (int t = 0; t < 4; t++)
#pragma unroll
      for (int e = 0; e < 4; e++) {
        float v = s[t][e];
        s[t][e] = v > 0.f ? v : 0.2f * v;
      }
    // ---- online softmax: row r = quad*4+e lives in the 16 lanes of `quad`
    float alpha[4];
#pragma unroll
    for (int e = 0; e < 4; e++) {
      float v = fmaxf(fmaxf(s[0][e], s[1][e]), fmaxf(s[2][e], s[3][e]));
      v = fmaxf(v, __shfl_xor(v, 1, 64));
      v = fmaxf(v, __shfl_xor(v, 2, 64));
      v = fmaxf(v, __shfl_xor(v, 4, 64));
      v = fmaxf(v, __shfl_xor(v, 8, 64));
      float mnew = fmaxf(m_run[e], v);
      alpha[e] = __expf(m_run[e] - mnew);
      m_run[e] = mnew;
    }
    float rs[4] = {0.f, 0.f, 0.f, 0.f};
#pragma unroll
    for (int t = 0; t < 4; t++)
#pragma unroll
      for (int e = 0; e < 4; e++) {
        float p = __expf(s[t][e] - m_run[e]);
        s[t][e] = p;
        rs[e] += p;
      }
#pragma unroll
    for (int e = 0; e < 4; e++) {
      float v = rs[e];
      v += __shfl_xor(v, 1, 64);
      v += __shfl_xor(v, 2, 64);
      v += __shfl_xor(v, 4, 64);
      v += __shfl_xor(v, 8, 64);
      l_run[e] = alpha[e] * l_run[e] + v;
    }
#pragma unroll
    for (int ct = 0; ct < 8; ct++)
#pragma unroll
      for (int e = 0; e < 4; e++) o[ct][e] *= alpha[e];

    // ---- P: C-layout -> A-layout via per-wave LDS region (intra-wave only)
    _Float16* Pw = Psh + wave * 1152;       // 16 rows x 72 halves
#pragma unroll
    for (int t = 0; t < 4; t++)
#pragma unroll
      for (int e = 0; e < 4; e++)
        Pw[(quad * 4 + e) * 72 + t * 16 + n16] = (_Float16)s[t][e];
    asm volatile("s_waitcnt lgkmcnt(0)" ::: "memory");
    f16x8 pa[2];
#pragma unroll
    for (int c = 0; c < 2; c++)
      pa[c] = *(const f16x8*)&Pw[n16 * 72 + c * 32 + quad * 8];

    // ---- O += P V : 8 col-tiles x 2 key-chunks
#pragma unroll
    for (int ct = 0; ct < 8; ct++)
#pragma unroll
      for (int c = 0; c < 2; c++) {
        f16x8 vf = *(const f16x8*)&Vtsh[(ct * 16 + n16) * 72 + c * 32 + quad * 8];
        o[ct] = __builtin_amdgcn_mfma_f32_16x16x32_f16(pa[c], vf, o[ct], 0, 0, 0);
      }
  }

  // ---- write unnormalized partials for this key-split
  const int sp = blockIdx.y;
  float* Op = Opart + (size_t)sp * SEQ * DIM;
#pragma unroll
  for (int ct = 0; ct < 8; ct++)
#pragma unroll
    for (int e = 0; e < 4; e++) {
      int row = qbase + quad * 4 + e;
      Op[(size_t)row * DIM + ct * 16 + n16] = o[ct][e];
    }
  if (n16 == 0) {
#pragma unroll
    for (int e = 0; e < 4; e++) {
      int row = qbase + quad * 4 + e;
      mpart[sp * SEQ + row] = m_run[e];
      lpart[sp * SEQ + row] = l_run[e];
    }
  }
}

// ---------------------------------------------------------------------------
// Kernel 3: log-sum-exp combine of NSPLIT partials -> out fp32
// ---------------------------------------------------------------------------
__global__ __launch_bounds__(256) void combine_kernel(
    const float* __restrict__ Opart, const float* __restrict__ mpart,
    const float* __restrict__ lpart, float* __restrict__ out) {
  int idx = blockIdx.x * 256 + threadIdx.x;   // 0 .. 8192*128-1
  int row = idx >> 7;
  float M = -1e30f;
#pragma unroll
  for (int p = 0; p < NSPLIT; p++) M = fmaxf(M, mpart[p * SEQ + row]);
  float num = 0.f, den = 0.f;
#pragma unroll
  for (int p = 0; p < NSPLIT; p++) {
    float e = __expf(mpart[p * SEQ + row] - M);
    den += e * lpart[p * SEQ + row];
    num += e * Opart[(size_t)p * SEQ * DIM + idx];
  }
  out[idx] = num / den;
}

// ---------------------------------------------------------------------------
extern "C" void kernel_launch(void* const* d_in, const int* in_sizes, int n_in,
                              void* d_out, int out_size, void* d_ws,
                              size_t ws_size, hipStream_t stream) {
  const float* h = (const float*)d_in[0];
  // d_in[1] = adj  (unused by the reference math)
  const float* W = (const float*)d_in[2];
  float* out = (float*)d_out;

  char* ws = (char*)d_ws;
  _Float16* Wh16  = (_Float16*)ws;                                  // 2 MiB
  _Float16* WhT16 = (_Float16*)(ws + (size_t)2 * 1024 * 1024);      // 2 MiB
  float* Opart = (float*)(ws + (size_t)4 * 1024 * 1024);            // 16 MiB
  float* mpart = (float*)(ws + (size_t)20 * 1024 * 1024);           // 128 KiB
  float* lpart = (float*)(ws + (size_t)20 * 1024 * 1024 + 128 * 1024);

  wh_kernel<<<SEQ / 8, 256, 0, stream>>>(h, W, Wh16, WhT16);
  dim3 grid(SEQ / BM, NSPLIT);
  flash_kernel<<<grid, 256, 0, stream>>>(Wh16, WhT16, Opart, mpart, lpart);
  combine_kernel<<<(SEQ * DIM) / 256, 256, 0, stream>>>(Opart, mpart, lpart, out);
}